// Round 6
// baseline (1715.852 us; speedup 1.0000x reference)
//
#include <hip/hip_runtime.h>

#define NM 1200
#define NMP 1280          // K padded to 20*64 for clean 64-k groups
#define PP 719400         // NM*(NM-1)/2
#define HID 128
#define RANK 64
#define SDP_ITERS 100
#define STATS_BLOCKS 1024

// ---------------- ws layout (floats) ----------------
// S[1600] | sumw2 | cvec[128] | W1s[5120] | wvec[PP] | Wmat[1200*1280] |
// Va[1280*64] | Vb[1280*64].  Spart aliases Wmat/Va/Vb region (consumed
// by reduce_S before buildW/v0norm/sdp write there).
#define OFF_S      0
#define OFF_SUMW2  1600
#define OFF_CVEC   1664
#define OFF_W1S    1792
#define OFF_WVEC   6912
#define OFF_WMAT   726400
#define OFF_VA     2262400
#define OFF_VB     2344320
#define OFF_SPART  726400     // 1024*1600 floats, aliased

__device__ __forceinline__ float wave_reduce_sum(float v) {
#pragma unroll
    for (int o = 32; o > 0; o >>= 1) v += __shfl_xor(v, o, 64);
    return v;
}

__global__ void zero1(float* __restrict__ p) { if (threadIdx.x == 0) p[0] = 0.f; }

// ---- pass 1: per-block partial S; NO global atomics (tail killer) ----
#define KT 40
__global__ __launch_bounds__(256) void stats_kernel(const float* __restrict__ x,
                                                    float* __restrict__ Spart) {
    __shared__ __align__(8) float tile[KT * 48];
    __shared__ float Sacc[48 * 48];
    const int tid = threadIdx.x;
    for (int i = tid; i < 48 * 48; i += 256) Sacc[i] = 0.f;

    const int rpb = (PP + STATS_BLOCKS - 1) / STATS_BLOCKS;  // 703
    const int r0 = blockIdx.x * rpb;
    const int r1 = min(r0 + rpb, PP);

    const int z  = tid >> 6;
    const int ln = tid & 63;
    const int ty = ln >> 3, tx = ln & 7;

    float acc[6][6];
#pragma unroll
    for (int a = 0; a < 6; ++a)
#pragma unroll
        for (int b = 0; b < 6; ++b) acc[a][b] = 0.f;

    for (int t = r0; t < r1; t += KT) {
        const int nr = min(KT, r1 - t);
        __syncthreads();
        const float* xg = x + (size_t)t * 39;
        for (int idx = tid; idx < KT * 48; idx += 256) {
            int rr = idx / 48, cc = idx - rr * 48;
            float v = 0.f;
            if (rr < nr) {
                if (cc < 39) v = xg[rr * 39 + cc];
                else if (cc == 39) v = 1.0f;
            }
            tile[idx] = v;
        }
        __syncthreads();
#pragma unroll 2
        for (int kk = 0; kk < KT / 4; ++kk) {
            const float* row = &tile[(kk * 4 + z) * 48];
            float2 a0 = *(const float2*)(row + ty * 6);
            float2 a1 = *(const float2*)(row + ty * 6 + 2);
            float2 a2 = *(const float2*)(row + ty * 6 + 4);
            float2 b0 = *(const float2*)(row + tx * 6);
            float2 b1 = *(const float2*)(row + tx * 6 + 2);
            float2 b2 = *(const float2*)(row + tx * 6 + 4);
            float av[6] = {a0.x, a0.y, a1.x, a1.y, a2.x, a2.y};
            float bv[6] = {b0.x, b0.y, b1.x, b1.y, b2.x, b2.y};
#pragma unroll
            for (int a = 0; a < 6; ++a)
#pragma unroll
                for (int b = 0; b < 6; ++b)
                    acc[a][b] = fmaf(av[a], bv[b], acc[a][b]);
        }
    }
    __syncthreads();
#pragma unroll
    for (int a = 0; a < 6; ++a)
#pragma unroll
        for (int b = 0; b < 6; ++b)
            atomicAdd(&Sacc[(ty * 6 + a) * 48 + tx * 6 + b], acc[a][b]);
    __syncthreads();
    float* out = Spart + (size_t)blockIdx.x * 1600;
    for (int i = tid; i < 1600; i += 256) {
        int r = i / 40, c = i - r * 40;
        out[i] = Sacc[r * 48 + c];
    }
}

// ---- reduce partials -> S[40x40] ----
__global__ __launch_bounds__(256) void reduce_S(const float* __restrict__ Spart,
                                                float* __restrict__ S) {
    const int j = blockIdx.x * 256 + threadIdx.x;
    if (j >= 1600) return;
    float s0 = 0.f, s1 = 0.f, s2 = 0.f, s3 = 0.f;
    for (int b = 0; b < STATS_BLOCKS; b += 4) {
        s0 += Spart[(size_t)b * 1600 + j];
        s1 += Spart[(size_t)(b + 1) * 1600 + j];
        s2 += Spart[(size_t)(b + 2) * 1600 + j];
        s3 += Spart[(size_t)(b + 3) * 1600 + j];
    }
    S[j] = (s0 + s1) + (s2 + s3);
}

// ---- BN folding ----
__global__ __launch_bounds__(64) void bn_prep(const float* __restrict__ S,
                                              const float* __restrict__ W1,
                                              const float* __restrict__ gamma,
                                              const float* __restrict__ beta,
                                              float* __restrict__ W1s,
                                              float* __restrict__ cvec) {
    const int j = blockIdx.x;
    const int l = threadIdx.x;
    const float invP = 1.0f / (float)PP;
    float q = 0.f;
    for (int idx = l; idx < 39 * 39; idx += 64) {
        int a = idx / 39, b = idx - a * 39;
        q = fmaf(S[a * 40 + b], W1[a * HID + j] * W1[b * HID + j], q);
    }
    float s1 = (l < 39) ? (S[39 * 40 + l] * invP) * W1[l * HID + j] : 0.f;
    q = wave_reduce_sum(q);
    s1 = wave_reduce_sum(s1);
    float var = q * invP - s1 * s1;
    float scale = gamma[j] * (1.0f / sqrtf(var + 1e-5f));
    for (int a = l; a < 39; a += 64) W1s[a * HID + j] = W1[a * HID + j] * scale;
    if (l == 0) cvec[j] = -s1 * scale + beta[j];
}

// ---- fused MLP: (256,1) frees the register allocator for the 64-acc strips ----
__global__ __launch_bounds__(256, 1) void mlp_kernel(const float* __restrict__ x,
                                                     const float* __restrict__ W1s,
                                                     const float* __restrict__ cvec,
                                                     const float* __restrict__ W2,
                                                     const float* __restrict__ b2,
                                                     float* __restrict__ w,
                                                     float* __restrict__ sumw2) {
    __shared__ float xt[256 * 39];
    __shared__ float red[4];
    const size_t base = (size_t)blockIdx.x * 256;
    {
        const size_t g0 = base * 39;
        const size_t gmax = (size_t)PP * 39;
        for (int idx = threadIdx.x; idx < 256 * 39; idx += 256) {
            size_t g = g0 + idx;
            xt[idx] = (g < gmax) ? x[g] : 0.f;
        }
    }
    __syncthreads();

    float xr[39];
    {
        const float* xrow = &xt[threadIdx.x * 39];
#pragma unroll
        for (int k = 0; k < 39; ++k) xr[k] = xrow[k];
    }

    float wacc = 0.f;
#pragma unroll 1
    for (int c = 0; c < 2; ++c) {
        float acc[64];
#pragma unroll
        for (int jj = 0; jj < 64; ++jj) acc[jj] = cvec[c * 64 + jj];
#pragma unroll 3
        for (int k = 0; k < 39; ++k) {
            const float xk = xr[k];
            const float* wrow = &W1s[k * HID + c * 64];
#pragma unroll
            for (int jj = 0; jj < 64; ++jj) acc[jj] = fmaf(xk, wrow[jj], acc[jj]);
        }
#pragma unroll
        for (int jj = 0; jj < 64; ++jj)
            wacc = fmaf(fmaxf(acc[jj], 0.f), W2[c * 64 + jj], wacc);
    }

    const size_t p = base + threadIdx.x;
    const float wv = wacc + b2[0];
    float sq = 0.f;
    if (p < (size_t)PP) { w[p] = wv; sq = wv * wv; }
    sq = wave_reduce_sum(sq);
    if ((threadIdx.x & 63) == 0) red[threadIdx.x >> 6] = sq;
    __syncthreads();
    if (threadIdx.x == 0) atomicAdd(sumw2, red[0] + red[1] + red[2] + red[3]);
}

// ---- W build: stride NMP, zero pad cols 1200..1279 ----
__global__ __launch_bounds__(256) void buildW(const float* __restrict__ w,
                                              float* __restrict__ W) {
    __shared__ float tile[16][17];
    const int bi = blockIdx.y, bj = blockIdx.x;   // bi<75, bj<80
    if (bi > bj) return;
    const int ty = threadIdx.x >> 4, tx = threadIdx.x & 15;
    const int i = bi * 16 + ty, j = bj * 16 + tx;
    float v = 0.f;
    if (i < j && j < NM) {
        int p = i * (NM - 1) - (i * (i - 1)) / 2 + (j - i - 1);
        v = w[p];
    }
    tile[ty][tx] = v;
    __syncthreads();
    if (bi == bj) {
        float o = (i < j) ? v : ((i > j) ? tile[tx][ty] : 0.f);
        W[(size_t)i * NMP + j] = o;
    } else {
        W[(size_t)i * NMP + j] = v;
        if (bj < 75)
            W[(size_t)(bj * 16 + ty) * NMP + (bi * 16 + tx)] = tile[tx][ty];
    }
}

// ---- V = V0 / ||row|| ----
__global__ __launch_bounds__(256) void v0norm(const float* __restrict__ V0,
                                              float* __restrict__ V) {
    const int i = blockIdx.x * 4 + (threadIdx.x >> 6);
    const int c = threadIdx.x & 63;
    float v = V0[(size_t)i * RANK + c];
    float s = wave_reduce_sum(v * v);
    V[(size_t)i * RANK + c] = v * (1.0f / sqrtf(s));
}

// ---- one SDP step: Vout = rownorm(Vin + lr * W @ Vin) ----
// 600 blocks x 256: block owns 2 rows; 4 waves = k-quarters of 320 (padded K).
// lane = col. W broadcast via v_readlane (VALU, immediate lane index);
// V read as one coalesced 256B dword load per k. Pad cols of W are 0, so
// pad V rows (poison, finite) contribute nothing.
__global__ __launch_bounds__(256) void sdp_step(const float* __restrict__ Vin,
                                                float* __restrict__ Vout,
                                                const float* __restrict__ W,
                                                const float* __restrict__ sumw2) {
    __shared__ float part[4][2][64];
    const int tid = threadIdx.x;
    const int c = tid & 63;
    const int kq = tid >> 6;
    const int i0 = blockIdx.x * 2;
    const float* __restrict__ W0 = W + (size_t)i0 * NMP;
    const float* __restrict__ W1 = W0 + NMP;

    float a0 = 0.f, a1 = 0.f, b0 = 0.f, b1 = 0.f;
    const int kbase = kq * 320;
#pragma unroll 1
    for (int g = 0; g < 5; ++g) {
        const int k0 = kbase + g * 64;
        const int w0i = __float_as_int(W0[k0 + c]);
        const int w1i = __float_as_int(W1[k0 + c]);
        const float* __restrict__ vp = Vin + (size_t)k0 * RANK + c;
#pragma unroll
        for (int t = 0; t < 64; t += 2) {
            float va = vp[(size_t)t * RANK];
            float vb = vp[(size_t)(t + 1) * RANK];
            float s0a = __int_as_float(__builtin_amdgcn_readlane(w0i, t));
            float s1a = __int_as_float(__builtin_amdgcn_readlane(w1i, t));
            float s0b = __int_as_float(__builtin_amdgcn_readlane(w0i, t + 1));
            float s1b = __int_as_float(__builtin_amdgcn_readlane(w1i, t + 1));
            a0 = fmaf(s0a, va, a0);
            a1 = fmaf(s1a, va, a1);
            b0 = fmaf(s0b, vb, b0);
            b1 = fmaf(s1b, vb, b1);
        }
    }
    part[kq][0][c] = a0 + b0;
    part[kq][1][c] = a1 + b1;
    __syncthreads();
    if (tid < 128) {
        const int r = tid >> 6, c2 = tid & 63;
        float s = part[0][r][c2] + part[1][r][c2] + part[2][r][c2] + part[3][r][c2];
        const float lr = 1.0f / (sqrtf(2.0f * sumw2[0]) + 1e-8f);
        float y = Vin[(size_t)(i0 + r) * RANK + c2] + lr * s;
        float n = wave_reduce_sum(y * y);
        Vout[(size_t)(i0 + r) * RANK + c2] = y * (1.0f / sqrtf(n));
    }
}

// ---- out = clip(V V^T, 0, 1): 128x128 symmetric tiles, 8x8 frags ----
__global__ __launch_bounds__(256) void vvt_kernel(const float* __restrict__ V,
                                                  float* __restrict__ out) {
    const int bi = blockIdx.y, bj = blockIdx.x;
    if (bi > bj) return;
    __shared__ __align__(16) float Ti[64][132];
    __shared__ __align__(16) float Tj[64][132];
    const int tid = threadIdx.x;
    for (int idx = tid; idx < 128 * 64; idx += 256) {
        int row = idx >> 6, k = idx & 63;
        int gi = bi * 128 + row, gj = bj * 128 + row;
        Ti[k][row] = (gi < NM) ? V[(size_t)gi * RANK + k] : 0.f;
        Tj[k][row] = (gj < NM) ? V[(size_t)gj * RANK + k] : 0.f;
    }
    __syncthreads();
    const int ty = tid >> 4, tx = tid & 15;
    float acc[8][8];
#pragma unroll
    for (int a = 0; a < 8; ++a)
#pragma unroll
        for (int b = 0; b < 8; ++b) acc[a][b] = 0.f;
    for (int k = 0; k < 64; ++k) {
        float4 a0 = *(const float4*)&Ti[k][ty * 8];
        float4 a1 = *(const float4*)&Ti[k][ty * 8 + 4];
        float4 b0 = *(const float4*)&Tj[k][tx * 8];
        float4 b1 = *(const float4*)&Tj[k][tx * 8 + 4];
        float av[8] = {a0.x, a0.y, a0.z, a0.w, a1.x, a1.y, a1.z, a1.w};
        float bv[8] = {b0.x, b0.y, b0.z, b0.w, b1.x, b1.y, b1.z, b1.w};
#pragma unroll
        for (int a = 0; a < 8; ++a)
#pragma unroll
            for (int b = 0; b < 8; ++b)
                acc[a][b] = fmaf(av[a], bv[b], acc[a][b]);
    }
#pragma unroll
    for (int a = 0; a < 8; ++a) {
        int i = bi * 128 + 8 * ty + a;
        if (i >= NM) break;
        int jb = bj * 128 + 8 * tx;
        if (jb + 7 < NM) {
            float4 s0 = {fminf(fmaxf(acc[a][0], 0.f), 1.f), fminf(fmaxf(acc[a][1], 0.f), 1.f),
                         fminf(fmaxf(acc[a][2], 0.f), 1.f), fminf(fmaxf(acc[a][3], 0.f), 1.f)};
            float4 s1 = {fminf(fmaxf(acc[a][4], 0.f), 1.f), fminf(fmaxf(acc[a][5], 0.f), 1.f),
                         fminf(fmaxf(acc[a][6], 0.f), 1.f), fminf(fmaxf(acc[a][7], 0.f), 1.f)};
            *(float4*)&out[(size_t)i * NM + jb] = s0;
            *(float4*)&out[(size_t)i * NM + jb + 4] = s1;
        } else {
#pragma unroll
            for (int b = 0; b < 8; ++b) {
                int j = jb + b;
                if (j < NM) out[(size_t)i * NM + j] = fminf(fmaxf(acc[a][b], 0.f), 1.f);
            }
        }
    }
    if (bi != bj) {
#pragma unroll
        for (int b = 0; b < 8; ++b) {
            int j = bj * 128 + 8 * tx + b;
            if (j >= NM) break;
            int ib = bi * 128 + 8 * ty;
            if (ib + 7 < NM) {
                float4 s0 = {fminf(fmaxf(acc[0][b], 0.f), 1.f), fminf(fmaxf(acc[1][b], 0.f), 1.f),
                             fminf(fmaxf(acc[2][b], 0.f), 1.f), fminf(fmaxf(acc[3][b], 0.f), 1.f)};
                float4 s1 = {fminf(fmaxf(acc[4][b], 0.f), 1.f), fminf(fmaxf(acc[5][b], 0.f), 1.f),
                             fminf(fmaxf(acc[6][b], 0.f), 1.f), fminf(fmaxf(acc[7][b], 0.f), 1.f)};
                *(float4*)&out[(size_t)j * NM + ib] = s0;
                *(float4*)&out[(size_t)j * NM + ib + 4] = s1;
            } else {
#pragma unroll
                for (int a = 0; a < 8; ++a) {
                    int i = ib + a;
                    if (i < NM) out[(size_t)j * NM + i] = fminf(fmaxf(acc[a][b], 0.f), 1.f);
                }
            }
        }
    }
}

extern "C" void kernel_launch(void* const* d_in, const int* in_sizes, int n_in,
                              void* d_out, int out_size, void* d_ws, size_t ws_size,
                              hipStream_t stream) {
    const float* x     = (const float*)d_in[0];
    const float* W1    = (const float*)d_in[1];
    const float* gamma = (const float*)d_in[3];
    const float* beta  = (const float*)d_in[4];
    const float* W2    = (const float*)d_in[5];
    const float* b2    = (const float*)d_in[6];
    const float* V0    = (const float*)d_in[7];
    float* out = (float*)d_out;

    float* ws    = (float*)d_ws;
    float* S     = ws + OFF_S;
    float* sumw2 = ws + OFF_SUMW2;
    float* cvec  = ws + OFF_CVEC;
    float* W1s   = ws + OFF_W1S;
    float* wvec  = ws + OFF_WVEC;
    float* Wmat  = ws + OFF_WMAT;
    float* Va    = ws + OFF_VA;
    float* Vb    = ws + OFF_VB;
    float* Spart = ws + OFF_SPART;

    zero1<<<1, 64, 0, stream>>>(sumw2);
    stats_kernel<<<STATS_BLOCKS, 256, 0, stream>>>(x, Spart);
    reduce_S<<<7, 256, 0, stream>>>(Spart, S);
    bn_prep<<<HID, 64, 0, stream>>>(S, W1, gamma, beta, W1s, cvec);
    mlp_kernel<<<(PP + 255) / 256, 256, 0, stream>>>(x, W1s, cvec, W2, b2, wvec, sumw2);
    buildW<<<dim3(80, 75), 256, 0, stream>>>(wvec, Wmat);
    v0norm<<<NM / 4, 256, 0, stream>>>(V0, Va);
    for (int it = 0; it < SDP_ITERS; ++it) {
        const float* vin = (it & 1) ? Vb : Va;
        float* vout      = (it & 1) ? Va : Vb;
        sdp_step<<<NM / 2, 256, 0, stream>>>(vin, vout, Wmat, sumw2);
    }
    // iter 99 (odd) writes Va
    vvt_kernel<<<dim3(10, 10), 256, 0, stream>>>(Va, out);
}